// Round 3
// baseline (294.831 us; speedup 1.0000x reference)
//
#include <hip/hip_runtime.h>
#include <stdint.h>

typedef unsigned short u16;
typedef unsigned int u32;

#define B_    2
#define DK    64
#define T_    2048
#define S_    2048
#define CI    512
#define CO    512
#define E_    512

typedef short  short8 __attribute__((ext_vector_type(8)));
typedef __bf16 bf16x8 __attribute__((ext_vector_type(8)));
typedef __bf16 bf16x4 __attribute__((ext_vector_type(4)));
typedef float  f32x4  __attribute__((ext_vector_type(4)));

// Native bf16 convert (RNE, identical to manual round-to-nearest-even bit trick,
// but compiles to v_cvt_pk_bf16_f32 pairs instead of ~4 VALU ops each).
static __device__ __forceinline__ u16 f2bf(float f) {
    return __builtin_bit_cast(u16, (__bf16)f);
}

static __device__ __forceinline__ float bf2f(u16 h) {
    return __uint_as_float((u32)h << 16);
}

static __device__ __forceinline__ short8 ld8(const u16* p) {
    return *(const short8*)p;
}

static __device__ __forceinline__ f32x4 mfma_bf16(short8 a, short8 b, f32x4 c) {
    return __builtin_amdgcn_mfma_f32_16x16x32_bf16(
        __builtin_bit_cast(bf16x8, a), __builtin_bit_cast(bf16x8, b), c, 0, 0, 0);
}

// ---------------- transpose + cvt: x[b][i][t] f32 -> xt[b][t][i] bf16 ----------------
__global__ __launch_bounds__(256) void k_transpose(const float* __restrict__ x,
                                                   const float* __restrict__ y,
                                                   u16* __restrict__ xt,
                                                   u16* __restrict__ yt) {
    __shared__ float tile[32][33];
    int tsel = blockIdx.z >> 1, b = blockIdx.z & 1;
    const float* src = tsel ? y : x;
    u16* dst = tsel ? yt : xt;
    int t0 = blockIdx.x * 32, i0 = blockIdx.y * 32;
    int tx = threadIdx.x & 31, ty = threadIdx.x >> 5;
#pragma unroll
    for (int r = 0; r < 4; r++) {
        int i = i0 + ty + r * 8;
        tile[ty + r * 8][tx] = src[(size_t)(b * CI + i) * T_ + t0 + tx];
    }
    __syncthreads();
#pragma unroll
    for (int r = 0; r < 4; r++) {
        int t = t0 + ty + r * 8;
        dst[(size_t)(b * T_ + t) * CI + i0 + tx] = f2bf(tile[tx][ty + r * 8]);
    }
}

// ---------------- mask transpose + pre-scale: mask[t][s] f32 -> mt[s][t] bf16*sc ----------------
__global__ __launch_bounds__(256) void k_maskt(const float* __restrict__ mask, u16* __restrict__ mt) {
    __shared__ float tile[32][33];
    int t0 = blockIdx.x * 32, s0 = blockIdx.y * 32;
    int tx = threadIdx.x & 31, ty = threadIdx.x >> 5;
    const float msc = 0.125f * 1.44269504088896f;
#pragma unroll
    for (int r = 0; r < 4; r++)
        tile[ty + r * 8][tx] = mask[(size_t)(t0 + ty + r * 8) * S_ + s0 + tx];
    __syncthreads();
#pragma unroll
    for (int r = 0; r < 4; r++)
        mt[(size_t)(s0 + ty + r * 8) * T_ + t0 + tx] = f2bf(tile[tx][ty + r * 8] * msc);
}

// ---------------- weight convert f32 -> bf16 ----------------
__global__ __launch_bounds__(256) void k_wconv(const float* __restrict__ wk, const float* __restrict__ wv,
                                               const float* __restrict__ wq, const float* __restrict__ wf,
                                               u16* __restrict__ wkb, u16* __restrict__ wvb,
                                               u16* __restrict__ wqb, u16* __restrict__ wfb) {
    int idx = blockIdx.x * 256 + threadIdx.x;
    int w = idx >> 18, off = idx & 262143;
    const float* s = (w == 0) ? wk : (w == 1) ? wv : (w == 2) ? wq : wf;
    u16* d = (w == 0) ? wkb : (w == 1) ? wvb : (w == 2) ? wqb : wfb;
    d[off] = f2bf(s[off]);
}

// ---------------- fused projection GEMMs ----------------
// p = p_base + (blockIdx.x>>8): 0=Q (yt->QT m0), 1=K (xt->KT m0), 2=V (xt->VT m1)
// block tile 64t x 128e, wave tile 32t x 64e
__global__ __launch_bounds__(256) void k_proj3(const u16* __restrict__ xt, const u16* __restrict__ yt,
                                               const u16* __restrict__ wkb, const u16* __restrict__ wvb,
                                               const u16* __restrict__ wqb,
                                               u16* __restrict__ ktd, u16* __restrict__ vtd,
                                               u16* __restrict__ qtd, int p_base) {
    int bi = blockIdx.x;
    int p = p_base + (bi >> 8);
    int r = bi & 255;
    int et = r & 3, tt = r >> 2;          // et: 128-e tile, tt: 64-t tile (b folded)
    int wv = threadIdx.x >> 6, lane = threadIdx.x & 63;
    int col = lane & 15, q = lane >> 4;
    int b = tt >> 5;
    int t0 = (tt & 31) * 64 + (wv >> 1) * 32;
    int e0 = et * 128 + (wv & 1) * 64;
    const u16* src = (p == 0) ? yt : xt;
    const u16* wb  = (p == 0) ? wqb : (p == 1) ? wkb : wvb;
    const u16* ap0 = src + (size_t)(b * T_ + t0 + col) * CI + q * 8;
    const u16* bp0 = wb + (size_t)(e0 + col) * CI + q * 8;
    f32x4 acc[2][4] = {};
#pragma unroll 4
    for (int ks = 0; ks < 16; ks++) {
        short8 a0 = ld8(ap0 + ks * 32);
        short8 a1 = ld8(ap0 + 16 * CI + ks * 32);
#pragma unroll
        for (int nt = 0; nt < 4; nt++) {
            short8 bb = ld8(bp0 + (size_t)(nt * 16) * CI + ks * 32);
            acc[0][nt] = mfma_bf16(a0, bb, acc[0][nt]);
            acc[1][nt] = mfma_bf16(a1, bb, acc[1][nt]);
        }
    }
    u16* dst = (p == 0) ? qtd : (p == 1) ? ktd : vtd;
    if (p < 2) {
#pragma unroll
        for (int mt = 0; mt < 2; mt++)
#pragma unroll
            for (int nt = 0; nt < 4; nt++) {
                int e = e0 + nt * 16 + col, h = e >> 6, k = e & 63;
                u16* dp = dst + ((size_t)(b * 8 + h) * T_ + t0 + mt * 16 + q * 4) * DK + k;
                dp[0] = f2bf(acc[mt][nt][0]);
                dp[DK] = f2bf(acc[mt][nt][1]);
                dp[2 * DK] = f2bf(acc[mt][nt][2]);
                dp[3 * DK] = f2bf(acc[mt][nt][3]);
            }
    } else {
#pragma unroll
        for (int mt = 0; mt < 2; mt++)
#pragma unroll
            for (int nt = 0; nt < 4; nt++) {
                int e = e0 + nt * 16 + col, h = e >> 6, v = e & 63;
                uint2 pk;
                pk.x = f2bf(acc[mt][nt][0]) | ((u32)f2bf(acc[mt][nt][1]) << 16);
                pk.y = f2bf(acc[mt][nt][2]) | ((u32)f2bf(acc[mt][nt][3]) << 16);
                *(uint2*)(dst + ((size_t)(b * 8 + h) * DK + v) * T_ + t0 + mt * 16 + q * 4) = pk;
            }
    }
}

// ---------------- flash attention, intra-block T-split, slim iteration ----------------
// MODE 1: mask from transposed pre-scaled bf16 MT[s][t] (2 coalesced 8B loads/iter).
// MODE 0: fallback, mask from f32 mask[t][s] (8 strided dword loads/iter).
// Per-iter slimming vs round 2: native cvt_pk bf16 casts, defer-rescale (THR=8,
// merge math exact for any reference m), deferred l cross-lane reduction (saves
// 2 shfl/iter), unroll-2 ping-pong K/mask prefetch (no register copies).
#define ATTN_ITER(T0, KC, MC, MC4, KN, MN, MN4, TN)  do {                          \
    short8 vb0 = ld8(vbase + (T0));                                                 \
    short8 vb1 = ld8(vbase + 16 * (size_t)T_ + (T0));                               \
    short8 vb2 = ld8(vbase + 32 * (size_t)T_ + (T0));                               \
    short8 vb3 = ld8(vbase + 48 * (size_t)T_ + (T0));                               \
    f32x4 z0 = {}, z1 = {};                                                         \
    f32x4 s0 = mfma_bf16(KC[0], bq0, z0);                                           \
    s0 = mfma_bf16(KC[1], bq1, s0);                                                 \
    f32x4 s1 = mfma_bf16(KC[2], bq0, z1);                                           \
    s1 = mfma_bf16(KC[3], bq1, s1);                                                 \
    KN[0] = ld8(kbase + (size_t)(TN) * DK);                                         \
    KN[1] = ld8(kbase + (size_t)(TN) * DK + 32);                                    \
    KN[2] = ld8(kbase + (size_t)((TN) + 16) * DK);                                  \
    KN[3] = ld8(kbase + (size_t)((TN) + 16) * DK + 32);                             \
    if constexpr (MODE == 1) {                                                      \
        MN4[0] = *(const ushort4*)(mtbase + (TN));                                  \
        MN4[1] = *(const ushort4*)(mtbase + (TN) + 16);                             \
    } else {                                                                        \
        _Pragma("unroll") for (int st = 0; st < 2; st++)                            \
        _Pragma("unroll") for (int rr = 0; rr < 4; rr++)                            \
            MN[st * 4 + rr] = mbase[(size_t)((TN) + st * 16 + q * 4 + rr) * S_] * sc; \
    }                                                                               \
    float vals[8];                                                                  \
    _Pragma("unroll") for (int i = 0; i < 8; i++) {                                 \
        float sv = (i < 4) ? s0[i & 3] : s1[i & 3];                                 \
        float mv;                                                                   \
        if constexpr (MODE == 1)                                                    \
            mv = bf2f(((const u16*)&MC4[i >> 2])[i & 3]);                           \
        else                                                                        \
            mv = MC[i];                                                             \
        vals[i] = fmaf(sv, sc, mv);                                                 \
    }                                                                               \
    float mx = fmaxf(fmaxf(fmaxf(vals[0], vals[1]), fmaxf(vals[2], vals[3])),       \
                     fmaxf(fmaxf(vals[4], vals[5]), fmaxf(vals[6], vals[7])));      \
    mx = fmaxf(mx, __shfl_xor(mx, 16));                                             \
    mx = fmaxf(mx, __shfl_xor(mx, 32));                                             \
    if (!__all(mx <= m_run + 8.f)) {                                                \
        float m_new = fmaxf(m_run, mx);                                             \
        float alpha = __builtin_amdgcn_exp2f(m_run - m_new);                        \
        Sm.lp.Al[wv][col] = alpha;                                                  \
        __builtin_amdgcn_wave_barrier();                                            \
        float4 ar = *(const float4*)&Sm.lp.Al[wv][q * 4];                           \
        _Pragma("unroll") for (int nt = 0; nt < 4; nt++) {                          \
            oacc[nt][0] *= ar.x; oacc[nt][1] *= ar.y;                               \
            oacc[nt][2] *= ar.z; oacc[nt][3] *= ar.w;                               \
        }                                                                           \
        l_part *= alpha;                                                            \
        m_run = m_new;                                                              \
    }                                                                               \
    bf16x4 pb0, pb1;                                                                \
    _Pragma("unroll") for (int i = 0; i < 4; i++) {                                 \
        float p = __builtin_amdgcn_exp2f(vals[i] - m_run);                          \
        l_part += p; pb0[i] = (__bf16)p;                                            \
    }                                                                               \
    _Pragma("unroll") for (int i = 0; i < 4; i++) {                                 \
        float p = __builtin_amdgcn_exp2f(vals[4 + i] - m_run);                      \
        l_part += p; pb1[i] = (__bf16)p;                                            \
    }                                                                               \
    *(unsigned long long*)&Sm.lp.Pl[wv][col][q * 4] =                               \
        __builtin_bit_cast(unsigned long long, pb0);                                \
    *(unsigned long long*)&Sm.lp.Pl[wv][col][16 + q * 4] =                          \
        __builtin_bit_cast(unsigned long long, pb1);                                \
    __builtin_amdgcn_wave_barrier();                                                \
    short8 pa = ld8(&Sm.lp.Pl[wv][col][q * 8]);                                     \
    oacc[0] = mfma_bf16(pa, vb0, oacc[0]);                                          \
    oacc[1] = mfma_bf16(pa, vb1, oacc[1]);                                          \
    oacc[2] = mfma_bf16(pa, vb2, oacc[2]);                                          \
    oacc[3] = mfma_bf16(pa, vb3, oacc[3]);                                          \
    __builtin_amdgcn_wave_barrier();                                                \
} while (0)

template<int MODE>
__global__ __launch_bounds__(256, 4) void k_attn(const u16* __restrict__ kt, const u16* __restrict__ qt,
                                                 const u16* __restrict__ vt, const float* __restrict__ mask,
                                                 const u16* __restrict__ mt, u16* __restrict__ oa) {
    __shared__ union {
        struct { u16 Pl[4][16][40]; float Al[4][16]; } lp;                        // 5376 B
        struct { float O[4][16][64]; float Ml[4][16][2]; float W[4][16]; } mg;    // 17152 B
    } Sm;
    int wv = threadIdx.x >> 6, lane = threadIdx.x & 63;
    int col = lane & 15, q = lane >> 4;
    int bh = blockIdx.x >> 7;
    int s_base = (blockIdx.x & 127) * 16;
    int sg = s_base + col;
    const int t_begin = wv * (T_ / 4);
    const int t_end = t_begin + (T_ / 4);
    const u16* qp = qt + (size_t)(bh * S_ + sg) * DK + q * 8;
    short8 bq0 = ld8(qp), bq1 = ld8(qp + 32);
    const u16* kbase = kt + (size_t)bh * T_ * DK + (size_t)col * DK + q * 8;
    const u16* vbase = vt + (size_t)bh * DK * T_ + (size_t)col * T_ + q * 8;
    const float* mbase = mask + sg;
    const u16* mtbase = mt + (size_t)sg * T_ + q * 4;
    float m_run = -1e30f, l_part = 0.f;
    f32x4 oacc[4] = {};
    const float sc = 0.125f * 1.44269504088896f;  // scale * log2(e)

    // prologue: K + mask for t_begin
    short8 kA[4], kB[4];
    float mA[8], mB[8];
    ushort4 mA4[2], mB4[2];
    kA[0] = ld8(kbase + (size_t)t_begin * DK);
    kA[1] = ld8(kbase + (size_t)t_begin * DK + 32);
    kA[2] = ld8(kbase + (size_t)(t_begin + 16) * DK);
    kA[3] = ld8(kbase + (size_t)(t_begin + 16) * DK + 32);
    if constexpr (MODE == 1) {
        mA4[0] = *(const ushort4*)(mtbase + t_begin);
        mA4[1] = *(const ushort4*)(mtbase + t_begin + 16);
    } else {
#pragma unroll
        for (int st = 0; st < 2; st++)
#pragma unroll
            for (int rr = 0; rr < 4; rr++)
                mA[st * 4 + rr] = mbase[(size_t)(t_begin + st * 16 + q * 4 + rr) * S_] * sc;
    }

    for (int t0 = t_begin; t0 < t_end; t0 += 64) {
        ATTN_ITER(t0, kA, mA, mA4, kB, mB, mB4, t0 + 32);
        int tn2 = (t0 + 64 < t_end) ? (t0 + 64) : t_begin;   // clamp: last prefetch unused
        ATTN_ITER(t0 + 32, kB, mB, mB4, kA, mA, mA4, tn2);
    }

    // deferred l cross-lane reduction (was 2 shfl per iter, now 2 total)
    l_part += __shfl_xor(l_part, 16);
    l_part += __shfl_xor(l_part, 32);

    // ---- merge of the 4 per-wave partials (exact flash merge, f32; holds for any
    // reference m_c, so defer-rescale does not change the math) ----
    __syncthreads();   // all waves done with lp phase before overlaying mg
#pragma unroll
    for (int nt = 0; nt < 4; nt++)
#pragma unroll
        for (int r = 0; r < 4; r++)
            Sm.mg.O[wv][q * 4 + r][nt * 16 + col] = oacc[nt][r];
    if (lane < 16) {
        Sm.mg.Ml[wv][lane][0] = m_run;
        Sm.mg.Ml[wv][lane][1] = l_part;
    }
    __syncthreads();
    if (lane < 16) {
        float m0 = Sm.mg.Ml[0][lane][0], m1 = Sm.mg.Ml[1][lane][0];
        float m2 = Sm.mg.Ml[2][lane][0], m3 = Sm.mg.Ml[3][lane][0];
        float ms = fmaxf(fmaxf(m0, m1), fmaxf(m2, m3));
        float w0 = __builtin_amdgcn_exp2f(m0 - ms), w1 = __builtin_amdgcn_exp2f(m1 - ms);
        float w2 = __builtin_amdgcn_exp2f(m2 - ms), w3 = __builtin_amdgcn_exp2f(m3 - ms);
        float ls = w0 * Sm.mg.Ml[0][lane][1] + w1 * Sm.mg.Ml[1][lane][1]
                 + w2 * Sm.mg.Ml[2][lane][1] + w3 * Sm.mg.Ml[3][lane][1];
        float inv = 1.f / ls;
        float wc = (wv == 0) ? w0 : (wv == 1) ? w1 : (wv == 2) ? w2 : w3;
        Sm.mg.W[wv][lane] = wc * inv;
    }
    __syncthreads();
    // wave wv owns output v-columns [wv*16, wv*16+16)
    int b = bh >> 3, h = bh & 7;
    float acc2[4] = {};
#pragma unroll
    for (int c = 0; c < 4; c++) {
        float4 wt4 = *(const float4*)&Sm.mg.W[c][q * 4];
#pragma unroll
        for (int r = 0; r < 4; r++) {
            float wr = (r == 0) ? wt4.x : (r == 1) ? wt4.y : (r == 2) ? wt4.z : wt4.w;
            acc2[r] += Sm.mg.O[c][q * 4 + r][wv * 16 + col] * wr;
        }
    }
#pragma unroll
    for (int r = 0; r < 4; r++) {
        int s = s_base + q * 4 + r;
        oa[(size_t)(b * S_ + s) * E_ + h * DK + wv * 16 + col] = f2bf(acc2[r]);
    }
}

// ---------------- final GEMM: out[b][s][o] = sum_v OA[b][s][v] * W[o][v] + bias[o] ----------------
// block tile 64s x 128o, wave tile 32s x 64o
__global__ __launch_bounds__(256) void k_final(const u16* __restrict__ oa, const u16* __restrict__ wfb,
                                               const float* __restrict__ bias, float* __restrict__ out) {
    int bi = blockIdx.x;
    int et = bi & 3, tt = bi >> 2;
    int wv = threadIdx.x >> 6, lane = threadIdx.x & 63;
    int col = lane & 15, q = lane >> 4;
    int b = tt >> 5;
    int s0 = (tt & 31) * 64 + (wv >> 1) * 32;
    int o0 = et * 128 + (wv & 1) * 64;
    const u16* ap0 = oa + (size_t)(b * S_ + s0 + col) * E_ + q * 8;
    const u16* bp0 = wfb + (size_t)(o0 + col) * E_ + q * 8;
    f32x4 acc[2][4] = {};
#pragma unroll 4
    for (int ks = 0; ks < 16; ks++) {
        short8 a0 = ld8(ap0 + ks * 32);
        short8 a1 = ld8(ap0 + 16 * E_ + ks * 32);
#pragma unroll
        for (int nt = 0; nt < 4; nt++) {
            short8 bb = ld8(bp0 + (size_t)(nt * 16) * E_ + ks * 32);
            acc[0][nt] = mfma_bf16(a0, bb, acc[0][nt]);
            acc[1][nt] = mfma_bf16(a1, bb, acc[1][nt]);
        }
    }
#pragma unroll
    for (int mt = 0; mt < 2; mt++)
#pragma unroll
        for (int nt = 0; nt < 4; nt++) {
            int o = o0 + nt * 16 + col;
            float bn = bias[o];
#pragma unroll
            for (int r = 0; r < 4; r++) {
                int s = s0 + mt * 16 + q * 4 + r;
                out[(size_t)(b * S_ + s) * CO + o] = acc[mt][nt][r] + bn;
            }
        }
}

extern "C" void kernel_launch(void* const* d_in, const int* in_sizes, int n_in,
                              void* d_out, int out_size, void* d_ws, size_t ws_size,
                              hipStream_t stream) {
    const float* x    = (const float*)d_in[0];
    const float* y    = (const float*)d_in[1];
    const float* mask = (const float*)d_in[2];
    const float* Wk   = (const float*)d_in[3];
    const float* Wv   = (const float*)d_in[4];
    const float* Wq   = (const float*)d_in[5];
    const float* Wf   = (const float*)d_in[6];
    const float* bias = (const float*)d_in[7];
    float* out = (float*)d_out;

    // Compact aliased layout — 18 MiB core + optional 8 MiB MT (mask^T bf16).
    u16* ws = (u16*)d_ws;
    u16* XT  = ws;                 // x^T bf16; reused as OA after projections
    u16* YT  = XT + 2097152;       // y^T bf16; reused as VT after Q projection
    u16* WKB = YT + 2097152;
    u16* WVB = WKB + 262144;
    u16* WQB = WVB + 262144;
    u16* WFB = WQB + 262144;
    u16* KT  = WFB + 262144;
    u16* QT  = KT + 2097152;       // end = 18 MiB
    u16* MT  = QT + 2097152;       // mask^T bf16 pre-scaled, end = 26 MiB
    u16* VT  = YT;                 // alias: YT dead after Q proj (launch 1)
    u16* OA  = XT;                 // alias: XT dead after K/V proj

    int use_mt = (ws_size >= (size_t)27262976) ? 1 : 0;   // 26 MiB needed for MT

    k_transpose<<<dim3(64, 16, 4), 256, 0, stream>>>(x, y, XT, YT);
    k_wconv<<<4096, 256, 0, stream>>>(Wk, Wv, Wq, Wf, WKB, WVB, WQB, WFB);
    if (use_mt)
        k_maskt<<<dim3(64, 64), 256, 0, stream>>>(mask, MT);
    // launch 1: Q (reads YT) + K (reads XT)
    k_proj3<<<512, 256, 0, stream>>>(XT, YT, WKB, WVB, WQB, KT, VT, QT, 0);
    // launch 2: V (reads XT, writes VT == YT — safe, launch 1 done with YT)
    k_proj3<<<256, 256, 0, stream>>>(XT, YT, WKB, WVB, WQB, KT, VT, QT, 2);
    if (use_mt)
        k_attn<1><<<2048, 256, 0, stream>>>(KT, QT, VT, mask, MT, OA);
    else
        k_attn<0><<<2048, 256, 0, stream>>>(KT, QT, VT, mask, MT, OA);
    k_final<<<256, 256, 0, stream>>>(OA, WFB, bias, out);
}

// Round 4
// 245.538 us; speedup vs baseline: 1.2008x; 1.2008x over previous
//
#include <hip/hip_runtime.h>
#include <stdint.h>

typedef unsigned short u16;
typedef unsigned int u32;

#define B_    2
#define DK    64
#define T_    2048
#define S_    2048
#define CI    512
#define CO    512
#define E_    512

typedef short  short8 __attribute__((ext_vector_type(8)));
typedef __bf16 bf16x8 __attribute__((ext_vector_type(8)));
typedef __bf16 bf16x4 __attribute__((ext_vector_type(4)));
typedef float  f32x4  __attribute__((ext_vector_type(4)));

static __device__ __forceinline__ u16 f2bf(float f) {
    return __builtin_bit_cast(u16, (__bf16)f);
}

static __device__ __forceinline__ float bf2f(u16 h) {
    return __uint_as_float((u32)h << 16);
}

static __device__ __forceinline__ short8 ld8(const u16* p) {
    return *(const short8*)p;
}

static __device__ __forceinline__ f32x4 mfma_bf16(short8 a, short8 b, f32x4 c) {
    return __builtin_amdgcn_mfma_f32_16x16x32_bf16(
        __builtin_bit_cast(bf16x8, a), __builtin_bit_cast(bf16x8, b), c, 0, 0, 0);
}

// ---------------- transpose + cvt: x[b][i][t] f32 -> xt[b][t][i] bf16 ----------------
__global__ __launch_bounds__(256) void k_transpose(const float* __restrict__ x,
                                                   const float* __restrict__ y,
                                                   u16* __restrict__ xt,
                                                   u16* __restrict__ yt) {
    __shared__ float tile[32][33];
    int tsel = blockIdx.z >> 1, b = blockIdx.z & 1;
    const float* src = tsel ? y : x;
    u16* dst = tsel ? yt : xt;
    int t0 = blockIdx.x * 32, i0 = blockIdx.y * 32;
    int tx = threadIdx.x & 31, ty = threadIdx.x >> 5;
#pragma unroll
    for (int r = 0; r < 4; r++) {
        int i = i0 + ty + r * 8;
        tile[ty + r * 8][tx] = src[(size_t)(b * CI + i) * T_ + t0 + tx];
    }
    __syncthreads();
#pragma unroll
    for (int r = 0; r < 4; r++) {
        int t = t0 + ty + r * 8;
        dst[(size_t)(b * T_ + t) * CI + i0 + tx] = f2bf(tile[tx][ty + r * 8]);
    }
}

// ---------------- mask transpose + pre-scale: mask[t][s] f32 -> mt[s][t] bf16*sc ----------------
__global__ __launch_bounds__(256) void k_maskt(const float* __restrict__ mask, u16* __restrict__ mt) {
    __shared__ float tile[32][33];
    int t0 = blockIdx.x * 32, s0 = blockIdx.y * 32;
    int tx = threadIdx.x & 31, ty = threadIdx.x >> 5;
    const float msc = 0.125f * 1.44269504088896f;
#pragma unroll
    for (int r = 0; r < 4; r++)
        tile[ty + r * 8][tx] = mask[(size_t)(t0 + ty + r * 8) * S_ + s0 + tx];
    __syncthreads();
#pragma unroll
    for (int r = 0; r < 4; r++)
        mt[(size_t)(s0 + ty + r * 8) * T_ + t0 + tx] = f2bf(tile[tx][ty + r * 8] * msc);
}

// ---------------- weight convert f32 -> bf16 ----------------
__global__ __launch_bounds__(256) void k_wconv(const float* __restrict__ wk, const float* __restrict__ wv,
                                               const float* __restrict__ wq, const float* __restrict__ wf,
                                               u16* __restrict__ wkb, u16* __restrict__ wvb,
                                               u16* __restrict__ wqb, u16* __restrict__ wfb) {
    int idx = blockIdx.x * 256 + threadIdx.x;
    int w = idx >> 18, off = idx & 262143;
    const float* s = (w == 0) ? wk : (w == 1) ? wv : (w == 2) ? wq : wf;
    u16* d = (w == 0) ? wkb : (w == 1) ? wvb : (w == 2) ? wqb : wfb;
    d[off] = f2bf(s[off]);
}

// ---------------- fused projection GEMMs ----------------
// p = p_base + (blockIdx.x>>8): 0=Q (yt->QT m0), 1=K (xt->KT m0), 2=V (xt->VT m1)
// block tile 64t x 128e, wave tile 32t x 64e
__global__ __launch_bounds__(256) void k_proj3(const u16* __restrict__ xt, const u16* __restrict__ yt,
                                               const u16* __restrict__ wkb, const u16* __restrict__ wvb,
                                               const u16* __restrict__ wqb,
                                               u16* __restrict__ ktd, u16* __restrict__ vtd,
                                               u16* __restrict__ qtd, int p_base) {
    int bi = blockIdx.x;
    int p = p_base + (bi >> 8);
    int r = bi & 255;
    int et = r & 3, tt = r >> 2;          // et: 128-e tile, tt: 64-t tile (b folded)
    int wv = threadIdx.x >> 6, lane = threadIdx.x & 63;
    int col = lane & 15, q = lane >> 4;
    int b = tt >> 5;
    int t0 = (tt & 31) * 64 + (wv >> 1) * 32;
    int e0 = et * 128 + (wv & 1) * 64;
    const u16* src = (p == 0) ? yt : xt;
    const u16* wb  = (p == 0) ? wqb : (p == 1) ? wkb : wvb;
    const u16* ap0 = src + (size_t)(b * T_ + t0 + col) * CI + q * 8;
    const u16* bp0 = wb + (size_t)(e0 + col) * CI + q * 8;
    f32x4 acc[2][4] = {};
#pragma unroll 4
    for (int ks = 0; ks < 16; ks++) {
        short8 a0 = ld8(ap0 + ks * 32);
        short8 a1 = ld8(ap0 + 16 * CI + ks * 32);
#pragma unroll
        for (int nt = 0; nt < 4; nt++) {
            short8 bb = ld8(bp0 + (size_t)(nt * 16) * CI + ks * 32);
            acc[0][nt] = mfma_bf16(a0, bb, acc[0][nt]);
            acc[1][nt] = mfma_bf16(a1, bb, acc[1][nt]);
        }
    }
    u16* dst = (p == 0) ? qtd : (p == 1) ? ktd : vtd;
    if (p < 2) {
#pragma unroll
        for (int mt = 0; mt < 2; mt++)
#pragma unroll
            for (int nt = 0; nt < 4; nt++) {
                int e = e0 + nt * 16 + col, h = e >> 6, k = e & 63;
                u16* dp = dst + ((size_t)(b * 8 + h) * T_ + t0 + mt * 16 + q * 4) * DK + k;
                dp[0] = f2bf(acc[mt][nt][0]);
                dp[DK] = f2bf(acc[mt][nt][1]);
                dp[2 * DK] = f2bf(acc[mt][nt][2]);
                dp[3 * DK] = f2bf(acc[mt][nt][3]);
            }
    } else {
#pragma unroll
        for (int mt = 0; mt < 2; mt++)
#pragma unroll
            for (int nt = 0; nt < 4; nt++) {
                int e = e0 + nt * 16 + col, h = e >> 6, v = e & 63;
                uint2 pk;
                pk.x = f2bf(acc[mt][nt][0]) | ((u32)f2bf(acc[mt][nt][1]) << 16);
                pk.y = f2bf(acc[mt][nt][2]) | ((u32)f2bf(acc[mt][nt][3]) << 16);
                *(uint2*)(dst + ((size_t)(b * 8 + h) * DK + v) * T_ + t0 + mt * 16 + q * 4) = pk;
            }
    }
}

// ---------------- flash attention: 32 s per wave, intra-block T-split, XCD-local bh ----------------
// Each wave owns a 32-s strip (two 16-s MFMA column groups sharing K/V registers:
// halves cache-side K/V traffic per output) over a T/4 chunk; 4 waves/block merge.
// Block decode groups all 64 s-blocks of 2 bh onto one XCD (blockIdx%8 heuristic)
// so K/V (2 MB per 2 bh) re-reads hit the 4 MiB per-XCD L2 instead of L3.
// __launch_bounds__(256,3): live state ~150 VGPR; cap 170 avoids spill (R1 lesson).

// softmax + PV for one 16-s group G; SA/SB = QK scores (t-sub 0/1), vb0..3 in scope.
#define SOFTPV(G, SA, SB, MC4, MCF) do {                                            \
    float vals[8];                                                                  \
    _Pragma("unroll") for (int i = 0; i < 8; i++) {                                 \
        float sv = (i < 4) ? SA[i & 3] : SB[i & 3];                                 \
        float mv;                                                                   \
        if constexpr (MODE == 1)                                                    \
            mv = bf2f(((const u16*)&MC4[G][i >> 2])[i & 3]);                        \
        else                                                                        \
            mv = MCF[G][i];                                                         \
        vals[i] = fmaf(sv, sc, mv);                                                 \
    }                                                                               \
    float mx = fmaxf(fmaxf(fmaxf(vals[0], vals[1]), fmaxf(vals[2], vals[3])),       \
                     fmaxf(fmaxf(vals[4], vals[5]), fmaxf(vals[6], vals[7])));      \
    mx = fmaxf(mx, __shfl_xor(mx, 16));                                             \
    mx = fmaxf(mx, __shfl_xor(mx, 32));                                             \
    if (!__all(mx <= m_run[G] + 8.f)) {                                             \
        float m_new = fmaxf(m_run[G], mx);                                          \
        float alpha = __builtin_amdgcn_exp2f(m_run[G] - m_new);                     \
        Sm.lp.Al[wv][G][col] = alpha;                                               \
        __builtin_amdgcn_wave_barrier();                                            \
        float4 ar = *(const float4*)&Sm.lp.Al[wv][G][q * 4];                        \
        _Pragma("unroll") for (int nt = 0; nt < 4; nt++) {                          \
            oacc[G][nt][0] *= ar.x; oacc[G][nt][1] *= ar.y;                         \
            oacc[G][nt][2] *= ar.z; oacc[G][nt][3] *= ar.w;                         \
        }                                                                           \
        l_part[G] *= alpha;                                                         \
        m_run[G] = m_new;                                                           \
    }                                                                               \
    bf16x4 pb0, pb1;                                                                \
    _Pragma("unroll") for (int i = 0; i < 4; i++) {                                 \
        float p = __builtin_amdgcn_exp2f(vals[i] - m_run[G]);                       \
        l_part[G] += p; pb0[i] = (__bf16)p;                                         \
    }                                                                               \
    _Pragma("unroll") for (int i = 0; i < 4; i++) {                                 \
        float p = __builtin_amdgcn_exp2f(vals[4 + i] - m_run[G]);                   \
        l_part[G] += p; pb1[i] = (__bf16)p;                                         \
    }                                                                               \
    *(unsigned long long*)&Sm.lp.Pl[wv][G][col][q * 4] =                            \
        __builtin_bit_cast(unsigned long long, pb0);                                \
    *(unsigned long long*)&Sm.lp.Pl[wv][G][col][16 + q * 4] =                       \
        __builtin_bit_cast(unsigned long long, pb1);                                \
    __builtin_amdgcn_wave_barrier();                                                \
    short8 pa = ld8(&Sm.lp.Pl[wv][G][col][q * 8]);                                  \
    oacc[G][0] = mfma_bf16(pa, vb0, oacc[G][0]);                                    \
    oacc[G][1] = mfma_bf16(pa, vb1, oacc[G][1]);                                    \
    oacc[G][2] = mfma_bf16(pa, vb2, oacc[G][2]);                                    \
    oacc[G][3] = mfma_bf16(pa, vb3, oacc[G][3]);                                    \
    __builtin_amdgcn_wave_barrier();                                                \
} while (0)

#define ATTN_ITER(T0, KC, MC4, MCF, KN, MN4, MNF, TN)  do {                         \
    short8 vb0 = ld8(vbase + (T0));                                                 \
    short8 vb1 = ld8(vbase + 16 * (size_t)T_ + (T0));                               \
    short8 vb2 = ld8(vbase + 32 * (size_t)T_ + (T0));                               \
    short8 vb3 = ld8(vbase + 48 * (size_t)T_ + (T0));                               \
    f32x4 z = {};                                                                   \
    f32x4 s00 = mfma_bf16(KC[0], q0a, z); s00 = mfma_bf16(KC[1], q0b, s00);         \
    f32x4 s01 = mfma_bf16(KC[2], q0a, z); s01 = mfma_bf16(KC[3], q0b, s01);         \
    f32x4 s10 = mfma_bf16(KC[0], q1a, z); s10 = mfma_bf16(KC[1], q1b, s10);         \
    f32x4 s11 = mfma_bf16(KC[2], q1a, z); s11 = mfma_bf16(KC[3], q1b, s11);         \
    KN[0] = ld8(kbase + (size_t)(TN) * DK);                                         \
    KN[1] = ld8(kbase + (size_t)(TN) * DK + 32);                                    \
    KN[2] = ld8(kbase + (size_t)((TN) + 16) * DK);                                  \
    KN[3] = ld8(kbase + (size_t)((TN) + 16) * DK + 32);                             \
    if constexpr (MODE == 1) {                                                      \
        MN4[0][0] = *(const ushort4*)(mtbase0 + (TN));                              \
        MN4[0][1] = *(const ushort4*)(mtbase0 + (TN) + 16);                         \
        MN4[1][0] = *(const ushort4*)(mtbase1 + (TN));                              \
        MN4[1][1] = *(const ushort4*)(mtbase1 + (TN) + 16);                         \
    } else {                                                                        \
        _Pragma("unroll") for (int st = 0; st < 2; st++)                            \
        _Pragma("unroll") for (int rr = 0; rr < 4; rr++) {                          \
            MNF[0][st * 4 + rr] = mbase0[(size_t)((TN) + st * 16 + q * 4 + rr) * S_] * sc; \
            MNF[1][st * 4 + rr] = mbase1[(size_t)((TN) + st * 16 + q * 4 + rr) * S_] * sc; \
        }                                                                           \
    }                                                                               \
    SOFTPV(0, s00, s01, MC4, MCF);                                                  \
    SOFTPV(1, s10, s11, MC4, MCF);                                                  \
} while (0)

template<int MODE>
__global__ __launch_bounds__(256, 3) void k_attn(const u16* __restrict__ kt, const u16* __restrict__ qt,
                                                 const u16* __restrict__ vt, const float* __restrict__ mask,
                                                 const u16* __restrict__ mt, u16* __restrict__ oa) {
    __shared__ union {
        struct { u16 Pl[4][2][16][40]; float Al[4][2][16]; } lp;                  // 10752 B
        struct { float O[4][16][64]; float Ml[4][16][2]; float W[4][16]; } mg;    // 17152 B
    } Sm;
    int wv = threadIdx.x >> 6, lane = threadIdx.x & 63;
    int col = lane & 15, q = lane >> 4;
    // XCD-local decode: blocks with blockIdx%8==x (heuristically XCD x) cover bh {2x,2x+1}
    int bid = blockIdx.x;
    int j = bid >> 3;
    int bh = (bid & 7) * 2 + (j >> 6);
    int s_base = (j & 63) * 32;
    int sg = s_base + col;
    const int t_begin = wv * (T_ / 4);
    const int t_end = t_begin + (T_ / 4);
    const u16* qp0 = qt + (size_t)(bh * S_ + sg) * DK + q * 8;
    short8 q0a = ld8(qp0), q0b = ld8(qp0 + 32);
    short8 q1a = ld8(qp0 + 16 * DK), q1b = ld8(qp0 + 16 * DK + 32);
    const u16* kbase = kt + (size_t)bh * T_ * DK + (size_t)col * DK + q * 8;
    const u16* vbase = vt + (size_t)bh * DK * T_ + (size_t)col * T_ + q * 8;
    const float* mbase0 = mask + sg;
    const float* mbase1 = mask + sg + 16;
    const u16* mtbase0 = mt + (size_t)sg * T_ + q * 4;
    const u16* mtbase1 = mtbase0 + (size_t)16 * T_;
    float m_run[2] = {-1e30f, -1e30f}, l_part[2] = {0.f, 0.f};
    f32x4 oacc[2][4] = {};
    const float sc = 0.125f * 1.44269504088896f;  // scale * log2(e)

    // prologue: K + mask for t_begin
    short8 kA[4], kB[4];
    ushort4 mA4[2][2], mB4[2][2];
    float mAf[2][8], mBf[2][8];
    kA[0] = ld8(kbase + (size_t)t_begin * DK);
    kA[1] = ld8(kbase + (size_t)t_begin * DK + 32);
    kA[2] = ld8(kbase + (size_t)(t_begin + 16) * DK);
    kA[3] = ld8(kbase + (size_t)(t_begin + 16) * DK + 32);
    if constexpr (MODE == 1) {
        mA4[0][0] = *(const ushort4*)(mtbase0 + t_begin);
        mA4[0][1] = *(const ushort4*)(mtbase0 + t_begin + 16);
        mA4[1][0] = *(const ushort4*)(mtbase1 + t_begin);
        mA4[1][1] = *(const ushort4*)(mtbase1 + t_begin + 16);
    } else {
#pragma unroll
        for (int st = 0; st < 2; st++)
#pragma unroll
            for (int rr = 0; rr < 4; rr++) {
                mAf[0][st * 4 + rr] = mbase0[(size_t)(t_begin + st * 16 + q * 4 + rr) * S_] * sc;
                mAf[1][st * 4 + rr] = mbase1[(size_t)(t_begin + st * 16 + q * 4 + rr) * S_] * sc;
            }
    }

    for (int t0 = t_begin; t0 < t_end; t0 += 64) {
        ATTN_ITER(t0, kA, mA4, mAf, kB, mB4, mBf, t0 + 32);
        int tn2 = (t0 + 64 < t_end) ? (t0 + 64) : t_begin;   // clamp: last prefetch unused
        ATTN_ITER(t0 + 32, kB, mB4, mBf, kA, mA4, mAf, tn2);
    }

    // deferred l cross-lane reduction (2 shfl per group, once total)
#pragma unroll
    for (int g = 0; g < 2; g++) {
        float lr = l_part[g];
        lr += __shfl_xor(lr, 16);
        lr += __shfl_xor(lr, 32);
        l_part[g] = lr;
    }

    // ---- merge of the 4 per-wave T-partials, one 16-s group at a time ----
    int b = bh >> 3, h = bh & 7;
    __syncthreads();   // all waves done with lp phase before overlaying mg
#pragma unroll
    for (int g = 0; g < 2; g++) {
#pragma unroll
        for (int nt = 0; nt < 4; nt++)
#pragma unroll
            for (int r = 0; r < 4; r++)
                Sm.mg.O[wv][q * 4 + r][nt * 16 + col] = oacc[g][nt][r];
        if (lane < 16) {
            Sm.mg.Ml[wv][lane][0] = m_run[g];
            Sm.mg.Ml[wv][lane][1] = l_part[g];
        }
        __syncthreads();
        if (lane < 16) {
            float m0 = Sm.mg.Ml[0][lane][0], m1 = Sm.mg.Ml[1][lane][0];
            float m2 = Sm.mg.Ml[2][lane][0], m3 = Sm.mg.Ml[3][lane][0];
            float ms = fmaxf(fmaxf(m0, m1), fmaxf(m2, m3));
            float w0 = __builtin_amdgcn_exp2f(m0 - ms), w1 = __builtin_amdgcn_exp2f(m1 - ms);
            float w2 = __builtin_amdgcn_exp2f(m2 - ms), w3 = __builtin_amdgcn_exp2f(m3 - ms);
            float ls = w0 * Sm.mg.Ml[0][lane][1] + w1 * Sm.mg.Ml[1][lane][1]
                     + w2 * Sm.mg.Ml[2][lane][1] + w3 * Sm.mg.Ml[3][lane][1];
            float inv = 1.f / ls;
            float wc = (wv == 0) ? w0 : (wv == 1) ? w1 : (wv == 2) ? w2 : w3;
            Sm.mg.W[wv][lane] = wc * inv;
        }
        __syncthreads();
        // wave wv owns output v-columns [wv*16, wv*16+16)
        float acc2[4] = {};
#pragma unroll
        for (int c = 0; c < 4; c++) {
            float4 wt4 = *(const float4*)&Sm.mg.W[c][q * 4];
#pragma unroll
            for (int r = 0; r < 4; r++) {
                float wr = (r == 0) ? wt4.x : (r == 1) ? wt4.y : (r == 2) ? wt4.z : wt4.w;
                acc2[r] += Sm.mg.O[c][q * 4 + r][wv * 16 + col] * wr;
            }
        }
#pragma unroll
        for (int r = 0; r < 4; r++) {
            int s = s_base + g * 16 + q * 4 + r;
            oa[(size_t)(b * S_ + s) * E_ + h * DK + wv * 16 + col] = f2bf(acc2[r]);
        }
        __syncthreads();   // O buffer reused by next group
    }
}

// ---------------- final GEMM: out[b][s][o] = sum_v OA[b][s][v] * W[o][v] + bias[o] ----------------
// block tile 64s x 128o, wave tile 32s x 64o
__global__ __launch_bounds__(256) void k_final(const u16* __restrict__ oa, const u16* __restrict__ wfb,
                                               const float* __restrict__ bias, float* __restrict__ out) {
    int bi = blockIdx.x;
    int et = bi & 3, tt = bi >> 2;
    int wv = threadIdx.x >> 6, lane = threadIdx.x & 63;
    int col = lane & 15, q = lane >> 4;
    int b = tt >> 5;
    int s0 = (tt & 31) * 64 + (wv >> 1) * 32;
    int o0 = et * 128 + (wv & 1) * 64;
    const u16* ap0 = oa + (size_t)(b * S_ + s0 + col) * E_ + q * 8;
    const u16* bp0 = wfb + (size_t)(o0 + col) * E_ + q * 8;
    f32x4 acc[2][4] = {};
#pragma unroll 4
    for (int ks = 0; ks < 16; ks++) {
        short8 a0 = ld8(ap0 + ks * 32);
        short8 a1 = ld8(ap0 + 16 * E_ + ks * 32);
#pragma unroll
        for (int nt = 0; nt < 4; nt++) {
            short8 bb = ld8(bp0 + (size_t)(nt * 16) * E_ + ks * 32);
            acc[0][nt] = mfma_bf16(a0, bb, acc[0][nt]);
            acc[1][nt] = mfma_bf16(a1, bb, acc[1][nt]);
        }
    }
#pragma unroll
    for (int mt = 0; mt < 2; mt++)
#pragma unroll
        for (int nt = 0; nt < 4; nt++) {
            int o = o0 + nt * 16 + col;
            float bn = bias[o];
#pragma unroll
            for (int r = 0; r < 4; r++) {
                int s = s0 + mt * 16 + q * 4 + r;
                out[(size_t)(b * S_ + s) * CO + o] = acc[mt][nt][r] + bn;
            }
        }
}

extern "C" void kernel_launch(void* const* d_in, const int* in_sizes, int n_in,
                              void* d_out, int out_size, void* d_ws, size_t ws_size,
                              hipStream_t stream) {
    const float* x    = (const float*)d_in[0];
    const float* y    = (const float*)d_in[1];
    const float* mask = (const float*)d_in[2];
    const float* Wk   = (const float*)d_in[3];
    const float* Wv   = (const float*)d_in[4];
    const float* Wq   = (const float*)d_in[5];
    const float* Wf   = (const float*)d_in[6];
    const float* bias = (const float*)d_in[7];
    float* out = (float*)d_out;

    // Compact aliased layout — 18 MiB core + optional 8 MiB MT (mask^T bf16).
    u16* ws = (u16*)d_ws;
    u16* XT  = ws;                 // x^T bf16; reused as OA after projections
    u16* YT  = XT + 2097152;       // y^T bf16; reused as VT after Q projection
    u16* WKB = YT + 2097152;
    u16* WVB = WKB + 262144;
    u16* WQB = WVB + 262144;
    u16* WFB = WQB + 262144;
    u16* KT  = WFB + 262144;
    u16* QT  = KT + 2097152;       // end = 18 MiB
    u16* MT  = QT + 2097152;       // mask^T bf16 pre-scaled, end = 26 MiB
    u16* VT  = YT;                 // alias: YT dead after Q proj (launch 1)
    u16* OA  = XT;                 // alias: XT dead after K/V proj

    int use_mt = (ws_size >= (size_t)27262976) ? 1 : 0;   // 26 MiB needed for MT

    k_transpose<<<dim3(64, 16, 4), 256, 0, stream>>>(x, y, XT, YT);
    k_wconv<<<4096, 256, 0, stream>>>(Wk, Wv, Wq, Wf, WKB, WVB, WQB, WFB);
    if (use_mt)
        k_maskt<<<dim3(64, 64), 256, 0, stream>>>(mask, MT);
    // launch 1: Q (reads YT) + K (reads XT)
    k_proj3<<<512, 256, 0, stream>>>(XT, YT, WKB, WVB, WQB, KT, VT, QT, 0);
    // launch 2: V (reads XT, writes VT == YT — safe, launch 1 done with YT)
    k_proj3<<<256, 256, 0, stream>>>(XT, YT, WKB, WVB, WQB, KT, VT, QT, 2);
    if (use_mt)
        k_attn<1><<<1024, 256, 0, stream>>>(KT, QT, VT, mask, MT, OA);
    else
        k_attn<0><<<1024, 256, 0, stream>>>(KT, QT, VT, mask, MT, OA);
    k_final<<<256, 256, 0, stream>>>(OA, WFB, bias, out);
}

// Round 5
// 212.815 us; speedup vs baseline: 1.3854x; 1.1538x over previous
//
#include <hip/hip_runtime.h>
#include <stdint.h>

typedef unsigned short u16;
typedef unsigned int u32;

#define B_    2
#define DK    64
#define T_    2048
#define S_    2048
#define CI    512
#define CO    512
#define E_    512

typedef short  short8 __attribute__((ext_vector_type(8)));
typedef __bf16 bf16x8 __attribute__((ext_vector_type(8)));
typedef __bf16 bf16x4 __attribute__((ext_vector_type(4)));
typedef float  f32x4  __attribute__((ext_vector_type(4)));

static __device__ __forceinline__ u16 f2bf(float f) {
    return __builtin_bit_cast(u16, (__bf16)f);
}

static __device__ __forceinline__ float bf2f(u16 h) {
    return __uint_as_float((u32)h << 16);
}

static __device__ __forceinline__ short8 ld8(const u16* p) {
    return *(const short8*)p;
}

static __device__ __forceinline__ f32x4 mfma_bf16(short8 a, short8 b, f32x4 c) {
    return __builtin_amdgcn_mfma_f32_16x16x32_bf16(
        __builtin_bit_cast(bf16x8, a), __builtin_bit_cast(bf16x8, b), c, 0, 0, 0);
}

// ---------------- transpose + cvt: x[b][i][t] f32 -> xt[b][t][i] bf16 ----------------
__global__ __launch_bounds__(256) void k_transpose(const float* __restrict__ x,
                                                   const float* __restrict__ y,
                                                   u16* __restrict__ xt,
                                                   u16* __restrict__ yt) {
    __shared__ float tile[32][33];
    int tsel = blockIdx.z >> 1, b = blockIdx.z & 1;
    const float* src = tsel ? y : x;
    u16* dst = tsel ? yt : xt;
    int t0 = blockIdx.x * 32, i0 = blockIdx.y * 32;
    int tx = threadIdx.x & 31, ty = threadIdx.x >> 5;
#pragma unroll
    for (int r = 0; r < 4; r++) {
        int i = i0 + ty + r * 8;
        tile[ty + r * 8][tx] = src[(size_t)(b * CI + i) * T_ + t0 + tx];
    }
    __syncthreads();
#pragma unroll
    for (int r = 0; r < 4; r++) {
        int t = t0 + ty + r * 8;
        dst[(size_t)(b * T_ + t) * CI + i0 + tx] = f2bf(tile[tx][ty + r * 8]);
    }
}

// ---------------- fused prep: weight cvt (bid<4096) + mask transpose/pre-scale ----------------
__global__ __launch_bounds__(256) void k_prep(const float* __restrict__ wk, const float* __restrict__ wv,
                                              const float* __restrict__ wq, const float* __restrict__ wf,
                                              const float* __restrict__ mask,
                                              u16* __restrict__ wkb, u16* __restrict__ wvb,
                                              u16* __restrict__ wqb, u16* __restrict__ wfb,
                                              u16* __restrict__ mt) {
    __shared__ float tile[32][33];
    int bid = blockIdx.x;
    if (bid < 4096) {
        int idx = bid * 256 + threadIdx.x;
        int w = idx >> 18, off = idx & 262143;
        const float* s = (w == 0) ? wk : (w == 1) ? wv : (w == 2) ? wq : wf;
        u16* d = (w == 0) ? wkb : (w == 1) ? wvb : (w == 2) ? wqb : wfb;
        d[off] = f2bf(s[off]);
    } else {
        int mb = bid - 4096;
        int t0 = (mb & 63) * 32, s0 = (mb >> 6) * 32;
        int tx = threadIdx.x & 31, ty = threadIdx.x >> 5;
        const float msc = 0.125f * 1.44269504088896f;
#pragma unroll
        for (int r = 0; r < 4; r++)
            tile[ty + r * 8][tx] = mask[(size_t)(t0 + ty + r * 8) * S_ + s0 + tx];
        __syncthreads();
#pragma unroll
        for (int r = 0; r < 4; r++)
            mt[(size_t)(s0 + ty + r * 8) * T_ + t0 + tx] = f2bf(tile[tx][ty + r * 8] * msc);
    }
}

// ---------------- fused projection GEMMs ----------------
// p = p_base + (blockIdx.x>>8): 0=Q (yt->QT m0), 1=K (xt->KT m0), 2=V (xt->VT m1)
// block tile 64t x 128e, wave tile 32t x 64e
__global__ __launch_bounds__(256) void k_proj3(const u16* __restrict__ xt, const u16* __restrict__ yt,
                                               const u16* __restrict__ wkb, const u16* __restrict__ wvb,
                                               const u16* __restrict__ wqb,
                                               u16* __restrict__ ktd, u16* __restrict__ vtd,
                                               u16* __restrict__ qtd, int p_base) {
    int bi = blockIdx.x;
    int p = p_base + (bi >> 8);
    int r = bi & 255;
    int et = r & 3, tt = r >> 2;          // et: 128-e tile, tt: 64-t tile (b folded)
    int wv = threadIdx.x >> 6, lane = threadIdx.x & 63;
    int col = lane & 15, q = lane >> 4;
    int b = tt >> 5;
    int t0 = (tt & 31) * 64 + (wv >> 1) * 32;
    int e0 = et * 128 + (wv & 1) * 64;
    const u16* src = (p == 0) ? yt : xt;
    const u16* wb  = (p == 0) ? wqb : (p == 1) ? wkb : wvb;
    const u16* ap0 = src + (size_t)(b * T_ + t0 + col) * CI + q * 8;
    const u16* bp0 = wb + (size_t)(e0 + col) * CI + q * 8;
    f32x4 acc[2][4] = {};
#pragma unroll 4
    for (int ks = 0; ks < 16; ks++) {
        short8 a0 = ld8(ap0 + ks * 32);
        short8 a1 = ld8(ap0 + 16 * CI + ks * 32);
#pragma unroll
        for (int nt = 0; nt < 4; nt++) {
            short8 bb = ld8(bp0 + (size_t)(nt * 16) * CI + ks * 32);
            acc[0][nt] = mfma_bf16(a0, bb, acc[0][nt]);
            acc[1][nt] = mfma_bf16(a1, bb, acc[1][nt]);
        }
    }
    u16* dst = (p == 0) ? qtd : (p == 1) ? ktd : vtd;
    if (p < 2) {
#pragma unroll
        for (int mt = 0; mt < 2; mt++)
#pragma unroll
            for (int nt = 0; nt < 4; nt++) {
                int e = e0 + nt * 16 + col, h = e >> 6, k = e & 63;
                u16* dp = dst + ((size_t)(b * 8 + h) * T_ + t0 + mt * 16 + q * 4) * DK + k;
                dp[0] = f2bf(acc[mt][nt][0]);
                dp[DK] = f2bf(acc[mt][nt][1]);
                dp[2 * DK] = f2bf(acc[mt][nt][2]);
                dp[3 * DK] = f2bf(acc[mt][nt][3]);
            }
    } else {
#pragma unroll
        for (int mt = 0; mt < 2; mt++)
#pragma unroll
            for (int nt = 0; nt < 4; nt++) {
                int e = e0 + nt * 16 + col, h = e >> 6, v = e & 63;
                uint2 pk;
                pk.x = f2bf(acc[mt][nt][0]) | ((u32)f2bf(acc[mt][nt][1]) << 16);
                pk.y = f2bf(acc[mt][nt][2]) | ((u32)f2bf(acc[mt][nt][3]) << 16);
                *(uint2*)(dst + ((size_t)(b * 8 + h) * DK + v) * T_ + t0 + mt * 16 + q * 4) = pk;
            }
    }
}

// ---------------- flash attention: 64 s per wave (4 groups), T-split, phase-split iter ----------------
// Each wave owns a 64-s strip = 4 independent 16-s groups sharing K/V registers
// (quarters the K/V cache-side traffic vs 16-s waves). Iteration is phase-split:
// all QK -> all softmax chains (independent, NO barriers between) -> one
// wave_barrier -> all P-reads+PV -> one barrier. R4's per-group barriers blocked
// chain interleaving; this exposes 4-way ILP to the scheduler.
// grid = 512 (16 bh x 32 strips), XCD-local: bid%8 -> bh pair, K/V fits 4MiB L2.
// __launch_bounds__(256,2): ~240 live VGPR; cap 256 avoids spill (R1 lesson).

#define ATTN_ITER(T0, KC, MC4, MCF, KN, MN4, MNF, TN)  do {                         \
    short8 vb0 = ld8(vbase + (T0));                                                 \
    short8 vb1 = ld8(vbase + 16 * (size_t)T_ + (T0));                               \
    short8 vb2 = ld8(vbase + 32 * (size_t)T_ + (T0));                               \
    short8 vb3 = ld8(vbase + 48 * (size_t)T_ + (T0));                               \
    f32x4 s0g[4], s1g[4];                                                           \
    _Pragma("unroll") for (int g = 0; g < 4; g++) {                                 \
        f32x4 z = {};                                                               \
        s0g[g] = mfma_bf16(KC[0], qa[g][0], z);                                     \
        s0g[g] = mfma_bf16(KC[1], qa[g][1], s0g[g]);                                \
        s1g[g] = mfma_bf16(KC[2], qa[g][0], z);                                     \
        s1g[g] = mfma_bf16(KC[3], qa[g][1], s1g[g]);                                \
    }                                                                               \
    KN[0] = ld8(kbase + (size_t)(TN) * DK);                                         \
    KN[1] = ld8(kbase + (size_t)(TN) * DK + 32);                                    \
    KN[2] = ld8(kbase + (size_t)((TN) + 16) * DK);                                  \
    KN[3] = ld8(kbase + (size_t)((TN) + 16) * DK + 32);                             \
    if constexpr (MODE == 1) {                                                      \
        _Pragma("unroll") for (int g = 0; g < 4; g++) {                             \
            MN4[g][0] = *(const ushort4*)(mtb[g] + (TN));                           \
            MN4[g][1] = *(const ushort4*)(mtb[g] + (TN) + 16);                      \
        }                                                                           \
    } else {                                                                        \
        _Pragma("unroll") for (int g = 0; g < 4; g++)                               \
        _Pragma("unroll") for (int st = 0; st < 2; st++)                            \
        _Pragma("unroll") for (int rr = 0; rr < 4; rr++)                            \
            MNF[g][st * 4 + rr] =                                                   \
                mbs[g][(size_t)((TN) + st * 16 + q * 4 + rr) * S_] * sc;            \
    }                                                                               \
    _Pragma("unroll") for (int g = 0; g < 4; g++) {                                 \
        float vals[8];                                                              \
        _Pragma("unroll") for (int i = 0; i < 8; i++) {                             \
            float sv = (i < 4) ? s0g[g][i & 3] : s1g[g][i & 3];                     \
            float mv;                                                               \
            if constexpr (MODE == 1)                                                \
                mv = bf2f(((const u16*)&MC4[g][i >> 2])[i & 3]);                    \
            else                                                                    \
                mv = MCF[g][i];                                                     \
            vals[i] = fmaf(sv, sc, mv);                                             \
        }                                                                           \
        float mx = fmaxf(fmaxf(fmaxf(vals[0], vals[1]), fmaxf(vals[2], vals[3])),   \
                         fmaxf(fmaxf(vals[4], vals[5]), fmaxf(vals[6], vals[7])));  \
        mx = fmaxf(mx, __shfl_xor(mx, 16));                                         \
        mx = fmaxf(mx, __shfl_xor(mx, 32));                                         \
        if (!__all(mx <= m_run[g] + 8.f)) {                                         \
            float m_new = fmaxf(m_run[g], mx);                                      \
            float alpha = __builtin_amdgcn_exp2f(m_run[g] - m_new);                 \
            Sm.lp.Al[wv][g][col] = alpha;                                           \
            __builtin_amdgcn_wave_barrier();                                        \
            float4 ar = *(const float4*)&Sm.lp.Al[wv][g][q * 4];                    \
            _Pragma("unroll") for (int nt = 0; nt < 4; nt++) {                      \
                oacc[g][nt][0] *= ar.x; oacc[g][nt][1] *= ar.y;                     \
                oacc[g][nt][2] *= ar.z; oacc[g][nt][3] *= ar.w;                     \
            }                                                                       \
            l_part[g] *= alpha;                                                     \
            m_run[g] = m_new;                                                       \
        }                                                                           \
        bf16x4 pb0, pb1;                                                            \
        _Pragma("unroll") for (int i = 0; i < 4; i++) {                             \
            float p = __builtin_amdgcn_exp2f(vals[i] - m_run[g]);                   \
            l_part[g] += p; pb0[i] = (__bf16)p;                                     \
        }                                                                           \
        _Pragma("unroll") for (int i = 0; i < 4; i++) {                             \
            float p = __builtin_amdgcn_exp2f(vals[4 + i] - m_run[g]);               \
            l_part[g] += p; pb1[i] = (__bf16)p;                                     \
        }                                                                           \
        *(unsigned long long*)&Sm.lp.Pl[wv][g][col][q * 4] =                        \
            __builtin_bit_cast(unsigned long long, pb0);                            \
        *(unsigned long long*)&Sm.lp.Pl[wv][g][col][16 + q * 4] =                   \
            __builtin_bit_cast(unsigned long long, pb1);                            \
    }                                                                               \
    __builtin_amdgcn_wave_barrier();                                                \
    _Pragma("unroll") for (int g = 0; g < 4; g++) {                                 \
        short8 pa = ld8(&Sm.lp.Pl[wv][g][col][q * 8]);                              \
        oacc[g][0] = mfma_bf16(pa, vb0, oacc[g][0]);                                \
        oacc[g][1] = mfma_bf16(pa, vb1, oacc[g][1]);                                \
        oacc[g][2] = mfma_bf16(pa, vb2, oacc[g][2]);                                \
        oacc[g][3] = mfma_bf16(pa, vb3, oacc[g][3]);                                \
    }                                                                               \
    __builtin_amdgcn_wave_barrier();                                                \
} while (0)

template<int MODE>
__global__ __launch_bounds__(256, 2) void k_attn(const u16* __restrict__ kt, const u16* __restrict__ qt,
                                                 const u16* __restrict__ vt, const float* __restrict__ mask,
                                                 const u16* __restrict__ mt, u16* __restrict__ oa) {
    __shared__ union {
        struct { u16 Pl[4][4][16][40]; float Al[4][4][16]; } lp;                  // 21504 B
        struct { float O[4][16][64]; float Ml[4][16][2]; float W[4][16]; } mg;    // 17152 B
    } Sm;
    int wv = threadIdx.x >> 6, lane = threadIdx.x & 63;
    int col = lane & 15, q = lane >> 4;
    // XCD-local decode: blocks with blockIdx%8==x cover bh {2x,2x+1}
    int bid = blockIdx.x;
    int j = bid >> 3;
    int bh = (bid & 7) * 2 + (j >> 5);
    int s_base = (j & 31) * 64;
    int sg = s_base + col;
    const int t_begin = wv * (T_ / 4);
    const int t_end = t_begin + (T_ / 4);
    short8 qa[4][2];
#pragma unroll
    for (int g = 0; g < 4; g++) {
        const u16* qp = qt + (size_t)(bh * S_ + sg + g * 16) * DK + q * 8;
        qa[g][0] = ld8(qp);
        qa[g][1] = ld8(qp + 32);
    }
    const u16* kbase = kt + (size_t)bh * T_ * DK + (size_t)col * DK + q * 8;
    const u16* vbase = vt + (size_t)bh * DK * T_ + (size_t)col * T_ + q * 8;
    const float* mbs[4];
    const u16* mtb[4];
#pragma unroll
    for (int g = 0; g < 4; g++) {
        mbs[g] = mask + sg + g * 16;
        mtb[g] = mt + (size_t)(sg + g * 16) * T_ + q * 4;
    }
    float m_run[4] = {-1e30f, -1e30f, -1e30f, -1e30f};
    float l_part[4] = {0.f, 0.f, 0.f, 0.f};
    f32x4 oacc[4][4] = {};
    const float sc = 0.125f * 1.44269504088896f;  // scale * log2(e)

    // prologue: K + mask for t_begin
    short8 kA[4], kB[4];
    ushort4 mA4[4][2], mB4[4][2];
    float mAf[4][8], mBf[4][8];
    kA[0] = ld8(kbase + (size_t)t_begin * DK);
    kA[1] = ld8(kbase + (size_t)t_begin * DK + 32);
    kA[2] = ld8(kbase + (size_t)(t_begin + 16) * DK);
    kA[3] = ld8(kbase + (size_t)(t_begin + 16) * DK + 32);
    if constexpr (MODE == 1) {
#pragma unroll
        for (int g = 0; g < 4; g++) {
            mA4[g][0] = *(const ushort4*)(mtb[g] + t_begin);
            mA4[g][1] = *(const ushort4*)(mtb[g] + t_begin + 16);
        }
    } else {
#pragma unroll
        for (int g = 0; g < 4; g++)
#pragma unroll
            for (int st = 0; st < 2; st++)
#pragma unroll
                for (int rr = 0; rr < 4; rr++)
                    mAf[g][st * 4 + rr] = mbs[g][(size_t)(t_begin + st * 16 + q * 4 + rr) * S_] * sc;
    }

    for (int t0 = t_begin; t0 < t_end; t0 += 64) {
        ATTN_ITER(t0, kA, mA4, mAf, kB, mB4, mBf, t0 + 32);
        int tn2 = (t0 + 64 < t_end) ? (t0 + 64) : t_begin;   // clamp: last prefetch unused
        ATTN_ITER(t0 + 32, kB, mB4, mBf, kA, mA4, mAf, tn2);
    }

    // deferred l cross-lane reduction
#pragma unroll
    for (int g = 0; g < 4; g++) {
        float lr = l_part[g];
        lr += __shfl_xor(lr, 16);
        lr += __shfl_xor(lr, 32);
        l_part[g] = lr;
    }

    // ---- merge of the 4 per-wave T-partials, one 16-s group at a time ----
    int b = bh >> 3, h = bh & 7;
    __syncthreads();   // all waves done with lp phase before overlaying mg
#pragma unroll
    for (int g = 0; g < 4; g++) {
#pragma unroll
        for (int nt = 0; nt < 4; nt++)
#pragma unroll
            for (int r = 0; r < 4; r++)
                Sm.mg.O[wv][q * 4 + r][nt * 16 + col] = oacc[g][nt][r];
        if (lane < 16) {
            Sm.mg.Ml[wv][lane][0] = m_run[g];
            Sm.mg.Ml[wv][lane][1] = l_part[g];
        }
        __syncthreads();
        if (lane < 16) {
            float m0 = Sm.mg.Ml[0][lane][0], m1 = Sm.mg.Ml[1][lane][0];
            float m2 = Sm.mg.Ml[2][lane][0], m3 = Sm.mg.Ml[3][lane][0];
            float ms = fmaxf(fmaxf(m0, m1), fmaxf(m2, m3));
            float w0 = __builtin_amdgcn_exp2f(m0 - ms), w1 = __builtin_amdgcn_exp2f(m1 - ms);
            float w2 = __builtin_amdgcn_exp2f(m2 - ms), w3 = __builtin_amdgcn_exp2f(m3 - ms);
            float ls = w0 * Sm.mg.Ml[0][lane][1] + w1 * Sm.mg.Ml[1][lane][1]
                     + w2 * Sm.mg.Ml[2][lane][1] + w3 * Sm.mg.Ml[3][lane][1];
            float inv = 1.f / ls;
            float wc = (wv == 0) ? w0 : (wv == 1) ? w1 : (wv == 2) ? w2 : w3;
            Sm.mg.W[wv][lane] = wc * inv;
        }
        __syncthreads();
        // wave wv owns output v-columns [wv*16, wv*16+16)
        float acc2[4] = {};
#pragma unroll
        for (int c = 0; c < 4; c++) {
            float4 wt4 = *(const float4*)&Sm.mg.W[c][q * 4];
#pragma unroll
            for (int r = 0; r < 4; r++) {
                float wr = (r == 0) ? wt4.x : (r == 1) ? wt4.y : (r == 2) ? wt4.z : wt4.w;
                acc2[r] += Sm.mg.O[c][q * 4 + r][wv * 16 + col] * wr;
            }
        }
#pragma unroll
        for (int r = 0; r < 4; r++) {
            int s = s_base + g * 16 + q * 4 + r;
            oa[(size_t)(b * S_ + s) * E_ + h * DK + wv * 16 + col] = f2bf(acc2[r]);
        }
        __syncthreads();   // O buffer reused by next group
    }
}

// ---------------- final GEMM: out[b][s][o] = sum_v OA[b][s][v] * W[o][v] + bias[o] ----------------
// block tile 64s x 128o, wave tile 32s x 64o
__global__ __launch_bounds__(256) void k_final(const u16* __restrict__ oa, const u16* __restrict__ wfb,
                                               const float* __restrict__ bias, float* __restrict__ out) {
    int bi = blockIdx.x;
    int et = bi & 3, tt = bi >> 2;
    int wv = threadIdx.x >> 6, lane = threadIdx.x & 63;
    int col = lane & 15, q = lane >> 4;
    int b = tt >> 5;
    int s0 = (tt & 31) * 64 + (wv >> 1) * 32;
    int o0 = et * 128 + (wv & 1) * 64;
    const u16* ap0 = oa + (size_t)(b * S_ + s0 + col) * E_ + q * 8;
    const u16* bp0 = wfb + (size_t)(o0 + col) * E_ + q * 8;
    f32x4 acc[2][4] = {};
#pragma unroll 4
    for (int ks = 0; ks < 16; ks++) {
        short8 a0 = ld8(ap0 + ks * 32);
        short8 a1 = ld8(ap0 + 16 * E_ + ks * 32);
#pragma unroll
        for (int nt = 0; nt < 4; nt++) {
            short8 bb = ld8(bp0 + (size_t)(nt * 16) * E_ + ks * 32);
            acc[0][nt] = mfma_bf16(a0, bb, acc[0][nt]);
            acc[1][nt] = mfma_bf16(a1, bb, acc[1][nt]);
        }
    }
#pragma unroll
    for (int mt = 0; mt < 2; mt++)
#pragma unroll
        for (int nt = 0; nt < 4; nt++) {
            int o = o0 + nt * 16 + col;
            float bn = bias[o];
#pragma unroll
            for (int r = 0; r < 4; r++) {
                int s = s0 + mt * 16 + q * 4 + r;
                out[(size_t)(b * S_ + s) * CO + o] = acc[mt][nt][r] + bn;
            }
        }
}

extern "C" void kernel_launch(void* const* d_in, const int* in_sizes, int n_in,
                              void* d_out, int out_size, void* d_ws, size_t ws_size,
                              hipStream_t stream) {
    const float* x    = (const float*)d_in[0];
    const float* y    = (const float*)d_in[1];
    const float* mask = (const float*)d_in[2];
    const float* Wk   = (const float*)d_in[3];
    const float* Wv   = (const float*)d_in[4];
    const float* Wq   = (const float*)d_in[5];
    const float* Wf   = (const float*)d_in[6];
    const float* bias = (const float*)d_in[7];
    float* out = (float*)d_out;

    // Layout (u16 units): 18 MiB core + 8 MiB MT + optional 4 MiB separate VT.
    u16* ws = (u16*)d_ws;
    u16* XT  = ws;                 // x^T bf16; reused as OA after projections
    u16* YT  = XT + 2097152;       // y^T bf16; fallback VT alias
    u16* WKB = YT + 2097152;
    u16* WVB = WKB + 262144;
    u16* WQB = WVB + 262144;
    u16* WFB = WQB + 262144;
    u16* KT  = WFB + 262144;
    u16* QT  = KT + 2097152;       // end = 18 MiB
    u16* MT  = QT + 2097152;       // mask^T bf16 pre-scaled, end = 26 MiB
    u16* VTs = MT + 4194304;       // separate V, end = 30 MiB
    u16* OA  = XT;                 // alias: XT dead after K/V proj

    int use_mt = (ws_size >= (size_t)27262976) ? 1 : 0;   // 26 MiB for MT
    int has_vt = (ws_size >= (size_t)31457280) ? 1 : 0;   // 30 MiB for separate VT
    u16* VT = has_vt ? VTs : YT;

    k_transpose<<<dim3(64, 16, 4), 256, 0, stream>>>(x, y, XT, YT);
    // fused weight-cvt (+ mask^T when workspace allows): grid controls which halves run
    k_prep<<<use_mt ? 8192 : 4096, 256, 0, stream>>>(Wk, Wv, Wq, Wf, mask,
                                                     WKB, WVB, WQB, WFB, MT);
    if (has_vt) {
        // single fused launch: Q (reads YT), K, V (writes separate VTs)
        k_proj3<<<768, 256, 0, stream>>>(XT, YT, WKB, WVB, WQB, KT, VT, QT, 0);
    } else {
        // launch 1: Q (reads YT) + K; launch 2: V (writes VT == YT, safe after launch 1)
        k_proj3<<<512, 256, 0, stream>>>(XT, YT, WKB, WVB, WQB, KT, VT, QT, 0);
        k_proj3<<<256, 256, 0, stream>>>(XT, YT, WKB, WVB, WQB, KT, VT, QT, 2);
    }
    if (use_mt)
        k_attn<1><<<512, 256, 0, stream>>>(KT, QT, VT, mask, MT, OA);
    else
        k_attn<0><<<512, 256, 0, stream>>>(KT, QT, VT, mask, MT, OA);
    k_final<<<256, 256, 0, stream>>>(OA, WFB, bias, out);
}